// Round 4
// baseline (659.470 us; speedup 1.0000x reference)
//
#include <hip/hip_runtime.h>
#include <hip/hip_bf16.h>

// GCN forward on MI355X — round 9: fuse spmm1+gemm2 (LDS tile, no h1r
// round-trip); restructure both SpMM gathers to 16-lane x 16B (4 edges in
// flight per chunk, es-prefetch pipeline, butterfly reduce).
//
//   prep:  w1t = bf16(w1^T) ∥ w2t = bf16(w2^T) ∥ hist (cur zeroed by memset)
//   scanA/B/C -> row_ptr/cursor
//   fused: scatter(es) ∥ gemm1 (h0b = bf16(x@w1+b1))
//   spmm1g2: h1 = relu(spmm(A, h0b)) [LDS] ; h2 = h1@w2t + b2 (MFMA)
//   spmm2: out = spmm(A, h2)

constexpr int N_NODES = 100000;
constexpr int IN_F    = 512;
constexpr int HID_F   = 128;
constexpr int N_CLS   = 64;
constexpr int N_EDGES = 1600000;

constexpr int SCAN_BLOCK    = 256;
constexpr int N_SCAN_BLOCKS = (N_NODES + SCAN_BLOCK - 1) / SCAN_BLOCK;  // 391

constexpr int NB_G1 = (N_NODES + 63) / 64;        // 1563 gemm1 blocks (64 rows)
constexpr int NB_SC = (N_EDGES + 1023) / 1024;    // 1563 scatter blocks
constexpr int NB_FUSED = NB_G1 + NB_SC;           // 3126
constexpr int NB_S1G2  = (N_NODES + 127) / 128;   // 782

typedef __attribute__((ext_vector_type(8))) short short8;
typedef __attribute__((ext_vector_type(4))) float f32x4;

static __device__ __forceinline__ unsigned short f2bf(float x) {
    unsigned int u = __float_as_uint(x);
    unsigned int r = (u + 0x7FFFu + ((u >> 16) & 1u)) >> 16;   // RNE
    return (unsigned short)r;
}
static __device__ __forceinline__ float bf2f(unsigned short u) {
    return __uint_as_float(((unsigned int)u) << 16);
}

// ---------------- prep: w1t ∥ w2t ∥ hist (cur pre-zeroed via memset) --------
__global__ __launch_bounds__(256) void prep_kernel(
    const float* __restrict__ w1, const float* __restrict__ w2,
    const int* __restrict__ row,
    unsigned short* __restrict__ w1t, unsigned short* __restrict__ w2t,
    int* __restrict__ counts)
{
    const int bid = blockIdx.x;
    if (bid < 256) {                               // w1t: 65536 elems, n-major
        int idx = bid * 256 + threadIdx.x;
        int n = idx >> 9, k = idx & 511;
        w1t[idx] = f2bf(w1[k * HID_F + n]);
    } else if (bid < 288) {                        // w2t: 8192 elems, n-major
        int idx = (bid - 256) * 256 + threadIdx.x;
        int n = idx >> 7, k = idx & 127;
        w2t[idx] = f2bf(w2[k * N_CLS + n]);
    } else {                                       // hist
        int e = (bid - 288) * 256 + threadIdx.x;
        if (e < N_EDGES) atomicAdd(&counts[row[e]], 1);
    }
}

// ---------------- CSR scans ----------------
__global__ __launch_bounds__(SCAN_BLOCK) void scanA_kernel(
    const int* __restrict__ counts, int* __restrict__ local_ex,
    int* __restrict__ blockSums)
{
    __shared__ int s[SCAN_BLOCK];
    const int t = threadIdx.x;
    const int i = blockIdx.x * SCAN_BLOCK + t;
    int v = (i < N_NODES) ? counts[i] : 0;
    s[t] = v;
    __syncthreads();
    for (int off = 1; off < SCAN_BLOCK; off <<= 1) {
        int u = (t >= off) ? s[t - off] : 0;
        __syncthreads();
        s[t] += u;
        __syncthreads();
    }
    if (i < N_NODES) local_ex[i] = s[t] - v;
    if (t == SCAN_BLOCK - 1) blockSums[blockIdx.x] = s[t];
}

__global__ __launch_bounds__(512) void scanB_kernel(int* __restrict__ blockSums)
{
    __shared__ int s[512];
    const int t = threadIdx.x;
    int v = (t < N_SCAN_BLOCKS) ? blockSums[t] : 0;
    s[t] = v;
    __syncthreads();
    for (int off = 1; off < 512; off <<= 1) {
        int u = (t >= off) ? s[t - off] : 0;
        __syncthreads();
        s[t] += u;
        __syncthreads();
    }
    if (t < N_SCAN_BLOCKS) blockSums[t] = s[t] - v;
}

__global__ __launch_bounds__(SCAN_BLOCK) void scanC_kernel(
    const int* __restrict__ local_ex, const int* __restrict__ blockSums,
    int* __restrict__ row_ptr, int* __restrict__ cursor)
{
    const int i = blockIdx.x * SCAN_BLOCK + threadIdx.x;
    if (i < N_NODES) {
        int v = local_ex[i] + blockSums[blockIdx.x];
        row_ptr[i] = v;
        cursor[i]  = v;
    }
    if (i == 0) row_ptr[N_NODES] = N_EDGES;
}

// ---------------- fused: scatter ∥ gemm1 ------------------------------------
__global__ __launch_bounds__(256, 4) void fused_g1_scatter_kernel(
    const float* __restrict__ x, const unsigned short* __restrict__ w1t,
    const float* __restrict__ b1, unsigned short* __restrict__ h0b,
    const int* __restrict__ row, const int* __restrict__ col,
    const float* __restrict__ val, int* __restrict__ cursor,
    int2* __restrict__ es)
{
    __shared__ unsigned short Bs[128 * 128];       // 32 KB
    char* lb = (char*)Bs;
    const int tid = threadIdx.x;
    const int bid = blockIdx.x;

    if (bid & 1) {
        // ---------------- scatter ----------------
        const int base = (bid >> 1) * 1024 + tid;
#pragma unroll
        for (int i = 0; i < 4; ++i) {
            int e = base + i * 256;
            if (e < N_EDGES) {
                int r = row[e];
                int pos = atomicAdd(&cursor[r], 1);
                es[pos] = make_int2(col[e], __float_as_int(val[e]));
            }
        }
        return;
    }

    // ---------------- gemm1 ----------------
    const int gid  = bid >> 1;
    const int lane = tid & 63;
    const int w    = tid >> 6;                     // 0..3
    const int m = lane & 15;
    const int q = lane >> 4;
    const int row0 = gid * 64;
    const int myrow = row0 + w * 16 + m;
    const int arow  = (myrow < N_NODES) ? myrow : (N_NODES - 1);

    f32x4 acc[8];
#pragma unroll
    for (int ni = 0; ni < 8; ++ni)
        acc[ni] = (f32x4){0.f, 0.f, 0.f, 0.f};

    union U8 { short8 v; __hip_bfloat162 h[4]; };

    const float* ap = x + (size_t)arow * IN_F + q * 8;
    const int swz = (m & 7) << 4;

    // 2-deep A prefetch: tiles 0 and 1
    float4 a0l = ((const float4*)ap)[0];
    float4 a0h = ((const float4*)ap)[1];
    float4 a1l = ((const float4*)(ap + 32))[0];
    float4 a1h = ((const float4*)(ap + 32))[1];

#pragma unroll
    for (int t = 0; t < 16; ++t) {
        if ((t & 3) == 0) {                        // stage phase p = t>>2
            if (t) __syncthreads();                // prev phase fully consumed
            const unsigned short* src = w1t + (t >> 2) * 128;
#pragma unroll
            for (int i = 0; i < 8; ++i) {
                int c = tid + i * 256;             // 0..2047 chunks of 16B
                int n = c >> 4, k16 = c & 15;
                short8 v = *(const short8*)(src + (size_t)n * IN_F + k16 * 8);
                *(short8*)(lb + ((n * 256 + k16 * 16) ^ ((n & 7) << 4))) = v;
            }
            __syncthreads();
        }

        // prefetch A tile t+2
        float4 nl, nh;
        if (t + 2 < 16) {
            nl = ((const float4*)(ap + (t + 2) * 32))[0];
            nh = ((const float4*)(ap + (t + 2) * 32))[1];
        }

        // convert current A tile to bf16 frag
        U8 u;
        u.h[0] = __float22bfloat162_rn(make_float2(a0l.x, a0l.y));
        u.h[1] = __float22bfloat162_rn(make_float2(a0l.z, a0l.w));
        u.h[2] = __float22bfloat162_rn(make_float2(a0h.x, a0h.y));
        u.h[3] = __float22bfloat162_rn(make_float2(a0h.z, a0h.w));
        short8 av = u.v;

        const int kb = (t & 3) * 64 + q * 16;      // byte offset of k in row
#pragma unroll
        for (int ni = 0; ni < 8; ++ni) {
            int off = (((ni * 16 + m) << 8) + kb) ^ swz;
            short8 bfr = *(const short8*)(lb + off);
            acc[ni] = __builtin_amdgcn_mfma_f32_16x16x32_bf16(av, bfr, acc[ni], 0, 0, 0);
        }

        a0l = a1l; a0h = a1h; a1l = nl; a1h = nh;  // rotate prefetch regs
    }

    // ---- epilogue: transpose C through LDS -> contiguous 16B stores ----
    __syncthreads();                               // done reading Bs
    {
        float bias[8];
#pragma unroll
        for (int ni = 0; ni < 8; ++ni) bias[ni] = b1[ni * 16 + m];

        char* cb = lb + w * 4352;                  // 16 rows x 272B (16B pad)
#pragma unroll
        for (int ni = 0; ni < 8; ++ni)
#pragma unroll
            for (int r = 0; r < 4; ++r)
                *(unsigned short*)(cb + (q * 4 + r) * 272 + (ni * 16 + m) * 2) =
                    f2bf(acc[ni][r] + bias[ni]);
    }
    __syncthreads();
#pragma unroll
    for (int i = 0; i < 4; ++i) {
        int c = tid + i * 256;                     // 0..1023: 64 rows x 16 ch
        int lr = c >> 4, c16 = c & 15;
        int grow = row0 + lr;
        if (grow < N_NODES) {
            short8 v = *(const short8*)(lb + (lr >> 4) * 4352 + (lr & 15) * 272 + c16 * 16);
            *(short8*)(h0b + (size_t)grow * HID_F + c16 * 8) = v;
        }
    }
}

// ---------------- fused spmm1 + gemm2 ---------------------------------------
// Block: 256 threads = 4 waves, 128 rows. Phase A: each wave gathers 32 rows
// (16-lane x 16B loads, 4 edges/chunk, es-prefetch pipeline, butterfly
// reduce), relu -> bf16 -> LDS tile (XOR-swizzled). Phase B: per-wave MFMA
// h2 = h1 @ w2t + b2 straight from LDS. No h1r global round-trip.
__global__ __launch_bounds__(256, 3) void spmm1_gemm2_kernel(
    const int* __restrict__ rp, const int2* __restrict__ es,
    const unsigned short* __restrict__ h0b,
    const unsigned short* __restrict__ w2t, const float* __restrict__ b2,
    float* __restrict__ h2)
{
    __shared__ unsigned short H1[128 * 128];       // 32 KB, swizzled
    __shared__ unsigned short W2[64 * 128];        // 16 KB, swizzled
    char* lh = (char*)H1;
    char* lw = (char*)W2;

    const int tid  = threadIdx.x;
    const int lane = tid & 63;
    const int w    = tid >> 6;                     // 0..3
    const int g    = lane >> 4;                    // edge slot 0..3
    const int l    = lane & 15;                    // 16B feature slot
    const int row0 = blockIdx.x * 128;

    // stage w2t (16 KB) — loads in flight under phase A
#pragma unroll
    for (int i = 0; i < 4; ++i) {
        int chunk = tid + i * 256;                 // 0..1023 chunks of 16B
        int n = chunk >> 4, k16 = chunk & 15;
        short8 v = *(const short8*)(w2t + (size_t)n * HID_F + k16 * 8);
        *(short8*)(lw + ((n * 256 + k16 * 16) ^ ((n & 7) << 4))) = v;
    }

    // ---- phase A: gather 32 rows per wave ----
    for (int rr = 0; rr < 32; ++rr) {
        const int r = row0 + w * 32 + rr;
        if (r < N_NODES) {
            const int j0 = rp[r], j1 = rp[r + 1];
            float acc[8] = {0.f, 0.f, 0.f, 0.f, 0.f, 0.f, 0.f, 0.f};
            int j = j0;
            if (j < j1) {
                int jj = j + g;
                int ci = jj < j1 ? jj : j1 - 1;
                int2 ec = es[ci];
                float vc = jj < j1 ? __int_as_float(ec.y) : 0.f;
                for (; j < j1; j += 4) {
                    int2 en = ec; float vn = 0.f;
                    if (j + 4 < j1) {              // prefetch next chunk's edge
                        int jn = j + 4 + g;
                        int cn = jn < j1 ? jn : j1 - 1;
                        en = es[cn];
                        vn = jn < j1 ? __int_as_float(en.y) : 0.f;
                    }
                    if (vc != 0.f) {               // group-uniform mask
                        union { short8 v; unsigned short u[8]; } hv;
                        hv.v = *(const short8*)(h0b + (size_t)ec.x * HID_F + l * 8);
#pragma unroll
                        for (int t = 0; t < 8; ++t)
                            acc[t] += vc * bf2f(hv.u[t]);
                    }
                    ec = en; vc = vn;
                }
            }
#pragma unroll
            for (int t = 0; t < 8; ++t) {          // reduce edge groups
                acc[t] += __shfl_xor(acc[t], 16, 64);
                acc[t] += __shfl_xor(acc[t], 32, 64);
            }
            if (g == 0) {                          // relu -> bf16 -> LDS
                union { short8 v; __hip_bfloat162 h[4]; } o;
                o.h[0] = __float22bfloat162_rn(make_float2(fmaxf(acc[0], 0.f), fmaxf(acc[1], 0.f)));
                o.h[1] = __float22bfloat162_rn(make_float2(fmaxf(acc[2], 0.f), fmaxf(acc[3], 0.f)));
                o.h[2] = __float22bfloat162_rn(make_float2(fmaxf(acc[4], 0.f), fmaxf(acc[5], 0.f)));
                o.h[3] = __float22bfloat162_rn(make_float2(fmaxf(acc[6], 0.f), fmaxf(acc[7], 0.f)));
                const int lr = w * 32 + rr;
                *(short8*)(lh + ((lr * 256 + l * 16) ^ ((lr & 7) << 4))) = o.v;
            }
        }
    }
    __syncthreads();

    // ---- phase B: h2 = h1 @ w2t + b2, 32 rows per wave ----
    const int m = lane & 15;
    const int q = lane >> 4;
    const int r0l = w * 32 + m;
    const int r1l = w * 32 + 16 + m;

    short8 a0[4], a1[4];
#pragma unroll
    for (int t = 0; t < 4; ++t) {
        a0[t] = *(const short8*)(lh + ((r0l * 256 + t * 64 + q * 16) ^ ((r0l & 7) << 4)));
        a1[t] = *(const short8*)(lh + ((r1l * 256 + t * 64 + q * 16) ^ ((r1l & 7) << 4)));
    }

    f32x4 acc2[2][4];
#pragma unroll
    for (int mi = 0; mi < 2; ++mi)
#pragma unroll
        for (int ni = 0; ni < 4; ++ni)
            acc2[mi][ni] = (f32x4){0.f, 0.f, 0.f, 0.f};

#pragma unroll
    for (int t = 0; t < 4; ++t) {
        const int kb = t * 64 + q * 16;
#pragma unroll
        for (int ni = 0; ni < 4; ++ni) {
            short8 b = *(const short8*)(lw + ((((ni * 16 + m) << 8) + kb) ^ ((m & 7) << 4)));
            acc2[0][ni] = __builtin_amdgcn_mfma_f32_16x16x32_bf16(a0[t], b, acc2[0][ni], 0, 0, 0);
            acc2[1][ni] = __builtin_amdgcn_mfma_f32_16x16x32_bf16(a1[t], b, acc2[1][ni], 0, 0, 0);
        }
    }

    float bias[4];
#pragma unroll
    for (int ni = 0; ni < 4; ++ni) bias[ni] = b2[ni * 16 + m];

#pragma unroll
    for (int mi = 0; mi < 2; ++mi)
#pragma unroll
        for (int rt = 0; rt < 4; ++rt) {
            int grow = row0 + w * 32 + mi * 16 + q * 4 + rt;
            if (grow < N_NODES) {
                float* dst = h2 + (size_t)grow * N_CLS;
#pragma unroll
                for (int ni = 0; ni < 4; ++ni)
                    dst[ni * 16 + m] = acc2[mi][ni][rt] + bias[ni];
            }
        }
}

// ---------------- SpMM2 gather (F=64, 16-lane x 16B) ------------------------
__global__ __launch_bounds__(256) void spmm2_kernel(
    const int* __restrict__ rp, const int2* __restrict__ es,
    const float* __restrict__ src, float* __restrict__ dst)
{
    const int r = blockIdx.x * 4 + threadIdx.y;
    if (r >= N_NODES) return;
    const int lane = threadIdx.x;
    const int g = lane >> 4;                       // edge slot 0..3
    const int l = lane & 15;                       // float4 feature slot
    const int j0 = rp[r], j1 = rp[r + 1];

    float acc[4] = {0.f, 0.f, 0.f, 0.f};
    int j = j0;
    if (j < j1) {
        int jj = j + g;
        int ci = jj < j1 ? jj : j1 - 1;
        int2 ec = es[ci];
        float vc = jj < j1 ? __int_as_float(ec.y) : 0.f;
        for (; j < j1; j += 4) {
            int2 en = ec; float vn = 0.f;
            if (j + 4 < j1) {
                int jn = j + 4 + g;
                int cn = jn < j1 ? jn : j1 - 1;
                en = es[cn];
                vn = jn < j1 ? __int_as_float(en.y) : 0.f;
            }
            if (vc != 0.f) {
                float4 hv = *(const float4*)(src + (size_t)ec.x * N_CLS + l * 4);
                acc[0] += vc * hv.x;
                acc[1] += vc * hv.y;
                acc[2] += vc * hv.z;
                acc[3] += vc * hv.w;
            }
            ec = en; vc = vn;
        }
    }
#pragma unroll
    for (int t = 0; t < 4; ++t) {
        acc[t] += __shfl_xor(acc[t], 16, 64);
        acc[t] += __shfl_xor(acc[t], 32, 64);
    }
    if (g == 0)
        *(float4*)(dst + (size_t)r * N_CLS + l * 4) =
            make_float4(acc[0], acc[1], acc[2], acc[3]);
}

extern "C" void kernel_launch(void* const* d_in, const int* in_sizes, int n_in,
                              void* d_out, int out_size, void* d_ws, size_t ws_size,
                              hipStream_t stream)
{
    const float* x       = (const float*)d_in[0];
    const int*   adj_row = (const int*)  d_in[1];
    const int*   adj_col = (const int*)  d_in[2];
    const float* adj_val = (const float*)d_in[3];
    const float* w1      = (const float*)d_in[4];
    const float* b1      = (const float*)d_in[5];
    const float* w2      = (const float*)d_in[6];
    const float* b2      = (const float*)d_in[7];
    float*       out     = (float*)d_out;

    // workspace carve-up
    char* ws = (char*)d_ws;
    unsigned short* h0b   = (unsigned short*)ws;                  // 25.6 MB
    float*          h2    = (float*)(ws + 51200000);              // 25.6 MB
    int2*           es    = (int2*) (ws + 76800000);              // 12.8 MB
    int*            rp    = (int*)  (ws + 89600000);              // 400 KB + 4
    int*            cur   = (int*)  (ws + 90000016);              // 400 KB
    unsigned short* w1t   = (unsigned short*)(ws + 90400016);     // 128 KB
    int*            lex   = (int*)  (ws + 90531088);              // 400 KB
    int*            bsum  = (int*)  (ws + 90931088);              // ~1.6 KB
    unsigned short* w2t   = (unsigned short*)(ws + 90932656);     // 16 KB

    // ---- prep ----
    hipMemsetAsync(cur, 0, N_NODES * sizeof(int), stream);
    prep_kernel<<<288 + (N_EDGES + 255) / 256, 256, 0, stream>>>(
        w1, w2, adj_row, w1t, w2t, cur);
    scanA_kernel<<<N_SCAN_BLOCKS, SCAN_BLOCK, 0, stream>>>(cur, lex, bsum);
    scanB_kernel<<<1, 512, 0, stream>>>(bsum);
    scanC_kernel<<<N_SCAN_BLOCKS, SCAN_BLOCK, 0, stream>>>(lex, bsum, rp, cur);

    // ---- conv1: scatter ∥ gemm1 fused ----
    fused_g1_scatter_kernel<<<NB_FUSED, 256, 0, stream>>>(
        x, w1t, b1, h0b, adj_row, adj_col, adj_val, cur, es);

    // ---- spmm1 + gemm2 fused ----
    spmm1_gemm2_kernel<<<NB_S1G2, 256, 0, stream>>>(rp, es, h0b, w2t, b2, h2);

    // ---- spmm2 ----
    spmm2_kernel<<<(N_NODES + 3) / 4, dim3(64, 4), 0, stream>>>(
        rp, es, h2, out);
}